// Round 1
// baseline (784.282 us; speedup 1.0000x reference)
//
#include <hip/hip_runtime.h>
#include <hip/hip_bf16.h>

#define NN 4096
#define FF 64
#define RR 4
#define KS 4

typedef __attribute__((ext_vector_type(8))) short bf16x8;
typedef __attribute__((ext_vector_type(4))) float f32x4;

__device__ __forceinline__ short f2bf(float f) {
  unsigned u = __builtin_bit_cast(unsigned, f);
  u = (u + 0x7fffu + ((u >> 16) & 1u)) >> 16;
  return (short)u;
}
__device__ __forceinline__ float bf2f(short s) {
  unsigned u = ((unsigned)(unsigned short)s) << 16;
  return __builtin_bit_cast(float, u);
}

// features [N][F] fp32 -> xfrag bf16 in B-fragment layout:
// xfrag[((kb*4 + t)*64 + lane)*8 + e] = x[kb*32 + 8*(lane>>4)+e][t*16 + (lane&15)]
__global__ void rgcn_prep(const float* __restrict__ feat, short* __restrict__ xfrag) {
  int kb = blockIdx.x;            // 0..127
  int t = threadIdx.x >> 6;       // 0..3
  int lane = threadIdx.x & 63;
  int lg = lane >> 4, li = lane & 15;
  bf16x8 pack;
#pragma unroll
  for (int e = 0; e < 8; e++) {
    int row = kb * 32 + lg * 8 + e;
    int col = t * 16 + li;
    pack[e] = f2bf(feat[row * FF + col]);
  }
  *(bf16x8*)(xfrag + (((size_t)(kb * 4 + t) * 64) + lane) * 8) = pack;
}

// agg partials: aggp[(ks*4+r)][n][f] = sum_{k in slice} A[r][n][k] * x[k][f]
__global__ __launch_bounds__(256) void rgcn_agg(const float* __restrict__ A,
                                                const short* __restrict__ xfrag,
                                                float* __restrict__ aggp) {
  int w = threadIdx.x >> 6, lane = threadIdx.x & 63;
  int lg = lane >> 4, li = lane & 15;
  int r = blockIdx.y, ks = blockIdx.z;
  int n0 = blockIdx.x * 64 + w * 16;
  const float* Arow = A + ((size_t)r * NN + (n0 + li)) * NN;

  f32x4 acc0 = 0.f, acc1 = 0.f, acc2 = 0.f, acc3 = 0.f;

#pragma unroll 2
  for (int kk = 0; kk < 1024 / 32; kk++) {
    int k0 = ks * 1024 + kk * 32;
    const float4* pa = (const float4*)(Arow + k0 + lg * 8);
    float4 v0 = pa[0], v1 = pa[1];
    bf16x8 a;
    a[0] = f2bf(v0.x); a[1] = f2bf(v0.y); a[2] = f2bf(v0.z); a[3] = f2bf(v0.w);
    a[4] = f2bf(v1.x); a[5] = f2bf(v1.y); a[6] = f2bf(v1.z); a[7] = f2bf(v1.w);
    int kb = k0 >> 5;
    const short* xb = xfrag + (size_t)kb * 4 * 64 * 8 + lane * 8;
    bf16x8 b0 = *(const bf16x8*)(xb + 0 * 64 * 8);
    bf16x8 b1 = *(const bf16x8*)(xb + 1 * 64 * 8);
    bf16x8 b2 = *(const bf16x8*)(xb + 2 * 64 * 8);
    bf16x8 b3 = *(const bf16x8*)(xb + 3 * 64 * 8);
    acc0 = __builtin_amdgcn_mfma_f32_16x16x32_bf16(a, b0, acc0, 0, 0, 0);
    acc1 = __builtin_amdgcn_mfma_f32_16x16x32_bf16(a, b1, acc1, 0, 0, 0);
    acc2 = __builtin_amdgcn_mfma_f32_16x16x32_bf16(a, b2, acc2, 0, 0, 0);
    acc3 = __builtin_amdgcn_mfma_f32_16x16x32_bf16(a, b3, acc3, 0, 0, 0);
  }

  int pidx = ks * RR + r;
  float* out = aggp + ((size_t)pidx * NN + n0) * FF;
  f32x4 accs[4] = {acc0, acc1, acc2, acc3};
#pragma unroll
  for (int t = 0; t < 4; t++)
#pragma unroll
    for (int i = 0; i < 4; i++)
      out[(4 * lg + i) * FF + t * 16 + li] = accs[t][i];
}

// y[n][g] = sum_{ks,r,f} aggp[ksr][n][f] * W[r][g][f]; x = sigmoid(y)
// writes xbf [N][F] bf16 and xfrag (fragment layout) for the next layer
__global__ __launch_bounds__(256) void rgcn_combine(const float* __restrict__ aggp,
                                                    const float* __restrict__ W,
                                                    short* __restrict__ xbf,
                                                    short* __restrict__ xfrag) {
  __shared__ float Wt[RR * FF * FF];  // [r][f][g]
  int tid = threadIdx.x;
  for (int idx = tid; idx < RR * FF * FF; idx += 256) {
    int r = idx >> 12, g = (idx >> 6) & 63, f = idx & 63;
    Wt[(r * FF + f) * FF + g] = W[idx];
  }
  __syncthreads();

  int nl = tid >> 6, g = tid & 63;
  int n = blockIdx.x * 4 + nl;
  float acc = 0.f;
  for (int ksr = 0; ksr < KS * RR; ksr++) {
    int r = ksr & 3;
    float av = aggp[((size_t)ksr * NN + n) * FF + g];  // lane g holds f=g
#pragma unroll
    for (int f = 0; f < FF; f++)
      acc += __shfl(av, f) * Wt[(r * FF + f) * FF + g];
  }
  float xv = 1.f / (1.f + __expf(-acc));
  xbf[n * FF + g] = f2bf(xv);
  int kb = n >> 5, kr = n & 31, lg2 = kr >> 3, e = kr & 7, t = g >> 4, li = g & 15;
  xfrag[(((size_t)(kb * 4 + t) * 64) + lg2 * 16 + li) * 8 + e] = f2bf(xv);
}

// xm[r][n][g] = sum_f x[n][f] * M[r][f][g]  (bf16 out)
__global__ __launch_bounds__(256) void rgcn_xm(const short* __restrict__ xbf,
                                               const float* __restrict__ M,
                                               short* __restrict__ xm) {
  __shared__ float Ml[FF * FF];  // [f][g]
  int tid = threadIdx.x;
  int r = blockIdx.y;
  for (int idx = tid; idx < FF * FF; idx += 256) Ml[idx] = M[r * FF * FF + idx];
  __syncthreads();
  int nl = tid >> 6, g = tid & 63;
  int n = blockIdx.x * 4 + nl;
  float xv = bf2f(xbf[n * FF + g]);
  float acc = 0.f;
#pragma unroll
  for (int f = 0; f < FF; f++) acc += __shfl(xv, f) * Ml[f * FF + g];
  xm[((size_t)r * NN + n) * FF + g] = f2bf(acc);
}

// res[r][n][m] = sum_g xm[r][n][g] * x[m][g]
__global__ __launch_bounds__(256) void rgcn_distmult(const short* __restrict__ xm,
                                                     const short* __restrict__ xbf,
                                                     float* __restrict__ out) {
  int w = threadIdx.x >> 6, lane = threadIdx.x & 63;
  int lg = lane >> 4, li = lane & 15;
  int r = blockIdx.z;
  int n0 = blockIdx.y * 64 + w * 16;
  int m0 = blockIdx.x * 64;

  const short* pa = xm + ((size_t)r * NN + n0 + li) * FF + lg * 8;
  bf16x8 a0 = *(const bf16x8*)(pa);
  bf16x8 a1 = *(const bf16x8*)(pa + 32);

  f32x4 acc0 = 0.f, acc1 = 0.f, acc2 = 0.f, acc3 = 0.f;
#pragma unroll
  for (int s = 0; s < 2; s++) {
    bf16x8 af = (s == 0) ? a0 : a1;
    const short* pb = xbf + (size_t)(m0 + li) * FF + s * 32 + lg * 8;
    bf16x8 b0 = *(const bf16x8*)(pb + 0 * 16 * FF);
    bf16x8 b1 = *(const bf16x8*)(pb + 1 * 16 * FF);
    bf16x8 b2 = *(const bf16x8*)(pb + 2 * 16 * FF);
    bf16x8 b3 = *(const bf16x8*)(pb + 3 * 16 * FF);
    acc0 = __builtin_amdgcn_mfma_f32_16x16x32_bf16(af, b0, acc0, 0, 0, 0);
    acc1 = __builtin_amdgcn_mfma_f32_16x16x32_bf16(af, b1, acc1, 0, 0, 0);
    acc2 = __builtin_amdgcn_mfma_f32_16x16x32_bf16(af, b2, acc2, 0, 0, 0);
    acc3 = __builtin_amdgcn_mfma_f32_16x16x32_bf16(af, b3, acc3, 0, 0, 0);
  }
  f32x4 accs[4] = {acc0, acc1, acc2, acc3};
#pragma unroll
  for (int t = 0; t < 4; t++)
#pragma unroll
    for (int i = 0; i < 4; i++)
      out[((size_t)r * NN + (n0 + 4 * lg + i)) * NN + m0 + t * 16 + li] = accs[t][i];
}

extern "C" void kernel_launch(void* const* d_in, const int* in_sizes, int n_in,
                              void* d_out, int out_size, void* d_ws, size_t ws_size,
                              hipStream_t stream) {
  const float* A = (const float*)d_in[0];     // [R][N][N]
  const float* feat = (const float*)d_in[1];  // [N][F]
  const float* Wc = (const float*)d_in[2];    // [L][R][F][F]
  const float* M = (const float*)d_in[3];     // [R][F][F]
  float* out = (float*)d_out;                 // [R][N][N]

  char* ws = (char*)d_ws;
  short* xfrag = (short*)ws;                   // 512 KB
  short* xbf   = (short*)(ws + (512 << 10));   // 512 KB
  short* xmb   = (short*)(ws + (1 << 20));     // 2 MB
  // agg partials live at the head of d_out (16 MB scratch, consumed before
  // distmult overwrites the full output). Stream-ordered, so no hazard.
  float* aggp = (float*)d_out;

  rgcn_prep<<<dim3(128), 256, 0, stream>>>(feat, xfrag);
  for (int l = 0; l < 2; l++) {
    rgcn_agg<<<dim3(64, RR, KS), 256, 0, stream>>>(A, xfrag, aggp);
    rgcn_combine<<<dim3(NN / 4), 256, 0, stream>>>(aggp, Wc + (size_t)l * RR * FF * FF, xbf, xfrag);
  }
  rgcn_xm<<<dim3(NN / 4, RR), 256, 0, stream>>>(xbf, M, xmb);
  rgcn_distmult<<<dim3(64, 64, RR), 256, 0, stream>>>(xmb, xbf, out);
}

// Round 2
// 673.930 us; speedup vs baseline: 1.1637x; 1.1637x over previous
//
#include <hip/hip_runtime.h>
#include <hip/hip_bf16.h>

#define NN 4096
#define FF 64
#define RR 4
#define KS 4

typedef __attribute__((ext_vector_type(8))) short bf16x8;
typedef __attribute__((ext_vector_type(4))) float f32x4;

__device__ __forceinline__ short f2bf(float f) {
  unsigned u = __builtin_bit_cast(unsigned, f);
  u = (u + 0x7fffu + ((u >> 16) & 1u)) >> 16;
  return (short)u;
}
__device__ __forceinline__ float bf2f(short s) {
  unsigned u = ((unsigned)(unsigned short)s) << 16;
  return __builtin_bit_cast(float, u);
}

// z_r = x @ W_r^T  (x fp32 [N][F], W [R][F_out][F_in]) -> zfrag bf16 in
// B-fragment layout: zfrag[r*N*F + ((kb*4+t)*64 + lg*16+li)*8 + e]
//   = z[kb*32 + lg*8 + e][t*16 + li]
// Also zeros y [N][F] fp32 (grid-stride over first 262144 gtids).
__global__ __launch_bounds__(256) void rgcn_z(const float* __restrict__ x,
                                              const float* __restrict__ W,
                                              short* __restrict__ zfrag,
                                              float* __restrict__ y) {
  int tid = threadIdx.x;
  int r = blockIdx.y;
  int gtid = (blockIdx.y * (NN / 4) + blockIdx.x) * 256 + tid;
  if (gtid < NN * FF) y[gtid] = 0.f;

  int nl = tid >> 6, g = tid & 63;
  int n = blockIdx.x * 4 + nl;
  const float* xr = x + n * FF;
  const float* wr = W + (r * FF + g) * FF;
  float acc = 0.f;
#pragma unroll
  for (int f = 0; f < FF; f += 4) {
    float4 xv = *(const float4*)(xr + f);
    float4 wv = *(const float4*)(wr + f);
    acc += xv.x * wv.x + xv.y * wv.y + xv.z * wv.z + xv.w * wv.w;
  }
  int kb = n >> 5, r5 = n & 31, lg = r5 >> 3, e = r5 & 7, t = g >> 4, li = g & 15;
  zfrag[(size_t)r * NN * FF + (((kb * 4 + t) * 64) + lg * 16 + li) * 8 + e] = f2bf(acc);
}

// y[n][g] += sum_{k in slice} A[r][n][k] * z_r[k][g]   (atomic fp32 accum)
__global__ __launch_bounds__(256) void rgcn_agg(const float* __restrict__ A,
                                                const short* __restrict__ zfrag,
                                                float* __restrict__ y) {
  int w = threadIdx.x >> 6, lane = threadIdx.x & 63;
  int lg = lane >> 4, li = lane & 15;
  int r = blockIdx.y, ks = blockIdx.z;
  int n0 = blockIdx.x * 64 + w * 16;
  const float* Arow = A + ((size_t)r * NN + (n0 + li)) * NN;
  const short* zf = zfrag + (size_t)r * NN * FF;

  f32x4 acc0 = 0.f, acc1 = 0.f, acc2 = 0.f, acc3 = 0.f;

#pragma unroll 2
  for (int kk = 0; kk < 1024 / 32; kk++) {
    int k0 = ks * 1024 + kk * 32;
    const float4* pa = (const float4*)(Arow + k0 + lg * 8);
    float4 v0 = pa[0], v1 = pa[1];
    bf16x8 a;
    a[0] = f2bf(v0.x); a[1] = f2bf(v0.y); a[2] = f2bf(v0.z); a[3] = f2bf(v0.w);
    a[4] = f2bf(v1.x); a[5] = f2bf(v1.y); a[6] = f2bf(v1.z); a[7] = f2bf(v1.w);
    int kb = k0 >> 5;
    const short* xb = zf + (size_t)kb * 4 * 64 * 8 + lane * 8;
    bf16x8 b0 = *(const bf16x8*)(xb + 0 * 64 * 8);
    bf16x8 b1 = *(const bf16x8*)(xb + 1 * 64 * 8);
    bf16x8 b2 = *(const bf16x8*)(xb + 2 * 64 * 8);
    bf16x8 b3 = *(const bf16x8*)(xb + 3 * 64 * 8);
    acc0 = __builtin_amdgcn_mfma_f32_16x16x32_bf16(a, b0, acc0, 0, 0, 0);
    acc1 = __builtin_amdgcn_mfma_f32_16x16x32_bf16(a, b1, acc1, 0, 0, 0);
    acc2 = __builtin_amdgcn_mfma_f32_16x16x32_bf16(a, b2, acc2, 0, 0, 0);
    acc3 = __builtin_amdgcn_mfma_f32_16x16x32_bf16(a, b3, acc3, 0, 0, 0);
  }

  float* yo = y + (size_t)n0 * FF;
  f32x4 accs[4] = {acc0, acc1, acc2, acc3};
#pragma unroll
  for (int t = 0; t < 4; t++)
#pragma unroll
    for (int i = 0; i < 4; i++)
      atomicAdd(&yo[(4 * lg + i) * FF + t * 16 + li], accs[t][i]);
}

// x = sigmoid(y): writes fp32 (next layer's Z input) and bf16 row-major
__global__ __launch_bounds__(256) void rgcn_sig(const float* __restrict__ y,
                                                float* __restrict__ xf,
                                                short* __restrict__ xbf) {
  int i = blockIdx.x * 256 + threadIdx.x;
  float v = 1.f / (1.f + __expf(-y[i]));
  xf[i] = v;
  xbf[i] = f2bf(v);
}

// xm[r][n][g] = sum_f x[n][f] * M[r][f][g]  (bf16 out, row-major)
__global__ __launch_bounds__(256) void rgcn_xm(const short* __restrict__ xbf,
                                               const float* __restrict__ M,
                                               short* __restrict__ xm) {
  int r = blockIdx.y;
  int nl = threadIdx.x >> 6, g = threadIdx.x & 63;
  int n = blockIdx.x * 4 + nl;
  const bf16x8* xr = (const bf16x8*)(xbf + n * FF);
  bf16x8 xv0 = xr[0], xv1 = xr[1], xv2 = xr[2], xv3 = xr[3];
  bf16x8 xv4 = xr[4], xv5 = xr[5], xv6 = xr[6], xv7 = xr[7];
  bf16x8 xv[8] = {xv0, xv1, xv2, xv3, xv4, xv5, xv6, xv7};
  const float* Mr = M + r * FF * FF;
  float acc = 0.f;
#pragma unroll
  for (int f = 0; f < FF; f++) acc += bf2f(xv[f >> 3][f & 7]) * Mr[f * FF + g];
  xm[((size_t)r * NN + n) * FF + g] = f2bf(acc);
}

// res[r][n][m] = sum_g xm[r][n][g] * x[m][g]
__global__ __launch_bounds__(256) void rgcn_distmult(const short* __restrict__ xm,
                                                     const short* __restrict__ xbf,
                                                     float* __restrict__ out) {
  int w = threadIdx.x >> 6, lane = threadIdx.x & 63;
  int lg = lane >> 4, li = lane & 15;
  int r = blockIdx.z;
  int n0 = blockIdx.y * 64 + w * 16;
  int m0 = blockIdx.x * 64;

  const short* pa = xm + ((size_t)r * NN + n0 + li) * FF + lg * 8;
  bf16x8 a0 = *(const bf16x8*)(pa);
  bf16x8 a1 = *(const bf16x8*)(pa + 32);

  f32x4 acc0 = 0.f, acc1 = 0.f, acc2 = 0.f, acc3 = 0.f;
#pragma unroll
  for (int s = 0; s < 2; s++) {
    bf16x8 af = (s == 0) ? a0 : a1;
    const short* pb = xbf + (size_t)(m0 + li) * FF + s * 32 + lg * 8;
    bf16x8 b0 = *(const bf16x8*)(pb + 0 * 16 * FF);
    bf16x8 b1 = *(const bf16x8*)(pb + 1 * 16 * FF);
    bf16x8 b2 = *(const bf16x8*)(pb + 2 * 16 * FF);
    bf16x8 b3 = *(const bf16x8*)(pb + 3 * 16 * FF);
    acc0 = __builtin_amdgcn_mfma_f32_16x16x32_bf16(af, b0, acc0, 0, 0, 0);
    acc1 = __builtin_amdgcn_mfma_f32_16x16x32_bf16(af, b1, acc1, 0, 0, 0);
    acc2 = __builtin_amdgcn_mfma_f32_16x16x32_bf16(af, b2, acc2, 0, 0, 0);
    acc3 = __builtin_amdgcn_mfma_f32_16x16x32_bf16(af, b3, acc3, 0, 0, 0);
  }
  f32x4 accs[4] = {acc0, acc1, acc2, acc3};
#pragma unroll
  for (int t = 0; t < 4; t++)
#pragma unroll
    for (int i = 0; i < 4; i++)
      out[((size_t)r * NN + (n0 + 4 * lg + i)) * NN + m0 + t * 16 + li] = accs[t][i];
}

extern "C" void kernel_launch(void* const* d_in, const int* in_sizes, int n_in,
                              void* d_out, int out_size, void* d_ws, size_t ws_size,
                              hipStream_t stream) {
  const float* A = (const float*)d_in[0];     // [R][N][N]
  const float* feat = (const float*)d_in[1];  // [N][F] fp32
  const float* Wc = (const float*)d_in[2];    // [L][R][F][F]
  const float* M = (const float*)d_in[3];     // [R][F][F]
  float* out = (float*)d_out;                 // [R][N][N]

  char* ws = (char*)d_ws;
  short* zfrag = (short*)ws;                      // 2 MB (bf16 [R][N][F] frag layout)
  float* y     = (float*)(ws + (2u << 20));       // 1 MB fp32 [N][F]
  float* xf    = (float*)(ws + (3u << 20));       // 1 MB fp32 [N][F]
  short* xbf   = (short*)(ws + (4u << 20));       // 512 KB bf16 [N][F]
  short* xmb   = (short*)(ws + (5u << 20));       // 2 MB bf16 [R][N][F]

  const float* xin = feat;
  for (int l = 0; l < 2; l++) {
    rgcn_z<<<dim3(NN / 4, RR), 256, 0, stream>>>(xin, Wc + (size_t)l * RR * FF * FF, zfrag, y);
    rgcn_agg<<<dim3(64, RR, KS), 256, 0, stream>>>(A, zfrag, y);
    rgcn_sig<<<dim3(NN * FF / 256), 256, 0, stream>>>(y, xf, xbf);
    xin = xf;
  }
  rgcn_xm<<<dim3(NN / 4, RR), 256, 0, stream>>>(xbf, M, xmb);
  rgcn_distmult<<<dim3(64, 64, RR), 256, 0, stream>>>(xmb, xbf, out);
}